// Round 12
// baseline (255.115 us; speedup 1.0000x reference)
//
#include <hip/hip_runtime.h>

typedef __attribute__((ext_vector_type(8))) short bf16x8;
typedef __attribute__((ext_vector_type(4))) short bf16x4;
typedef __attribute__((ext_vector_type(4))) float f32x4;

#if __has_builtin(__builtin_amdgcn_exp2f)
#define EXP2(x) __builtin_amdgcn_exp2f(x)
#else
#define EXP2(x) exp2f(x)
#endif

__device__ __forceinline__ unsigned short f2bf(float f) {
    union { float f; unsigned int u; } v; v.f = f;
    unsigned int r = v.u + 0x7fffu + ((v.u >> 16) & 1u);
    return (unsigned short)(r >> 16);
}

__device__ __forceinline__ float asf(unsigned int u) {
    union { unsigned int u; float f; } v; v.u = u; return v.f;
}

// sqrt( (1/sqrt(32)) * log2(e) ) — baked into BOTH xqT operands so QK^T
// emerges pre-multiplied by scale*log2e: exp2(raw score) == softmax numerator.
#define QK_PRESCALE 0.50500983f

// ---------------------------------------------------------------------------
// Kernel 1: grouped 1x1 conv, 1024 blocks.
// ---------------------------------------------------------------------------
__global__ __launch_bounds__(256) void conv_kernel(
    const float* __restrict__ points, const float* __restrict__ conv_w,
    const float* __restrict__ conv_b,
    unsigned short* __restrict__ xqT, unsigned short* __restrict__ xv)
{
    __shared__ float w[1024];
    const int h  = blockIdx.x >> 6;   // 16 heads
    const int nc = blockIdx.x & 63;   // 64 n-chunks of 64
    const int g  = h & 7;
    const int tid = threadIdx.x;
    const float* wg = conv_w + g * 1024;
    for (int k = tid; k < 1024; k += 256) w[k] = wg[k];
    __syncthreads();
    const int n  = nc * 64 + (tid & 63);
    const int ig = tid >> 6;          // wave id -> channels [ig*8, ig*8+8)
    const float* p = points + (size_t)h * 32 * 4096 + n;
    float pv[32];
#pragma unroll
    for (int j = 0; j < 32; ++j) pv[j] = p[(size_t)j * 4096];
    float out[8];
#pragma unroll
    for (int ii = 0; ii < 8; ++ii) {
        const int i = ig * 8 + ii;
        float acc = conv_b[g * 32 + i];
        const float4* w4 = (const float4*)(w + i * 32);   // ds_read_b128
#pragma unroll
        for (int j4 = 0; j4 < 8; ++j4) {
            float4 ww = w4[j4];
            acc += ww.x * pv[j4 * 4]     + ww.y * pv[j4 * 4 + 1]
                 + ww.z * pv[j4 * 4 + 2] + ww.w * pv[j4 * 4 + 3];
        }
        out[ii] = acc;
    }
    unsigned short tq[8];
#pragma unroll
    for (int ii = 0; ii < 8; ++ii) tq[ii] = f2bf(out[ii] * QK_PRESCALE);
    *(bf16x8*)(xqT + ((size_t)h * 4096 + n) * 32 + ig * 8) = *(bf16x8*)tq;
#pragma unroll
    for (int ii = 0; ii < 8; ++ii) {
        float x = out[ii];
        float e = x > 0.f ? x : (__expf(x) - 1.f);   // elu
        xv[((size_t)h * 32 + ig * 8 + ii) * 4096 + n] = f2bf(e);
    }
}

// ---------------------------------------------------------------------------
// Kernel 2: flash attention, BARRIER-FREE. 1024 blocks, 4096 keys/block.
// K fragments: direct global->reg, double-buffered one chunk ahead (R9).
// V fragments: direct global->reg, issued at chunk top, consumed after the
// 4-step QK/exp phase (~300+ cyc cover; xv is L2-resident + XCD-swizzled).
// P: per-wave LDS round-trip only (intra-wave, lgkmcnt-ordered).
// ZERO __syncthreads -> waves slip freely, no lockstep barrier drains
// (R7-R11: every pipe diet was neutral; 44% no-issue was the barrier chain).
// Epilogue: normalize, channel shuffle, +residual, private-slot GN partials.
// ---------------------------------------------------------------------------
#define PSTR 72    // 64 + 8 pad shorts

#if __has_builtin(__builtin_amdgcn_cvt_pk_bf16_f32)
typedef __attribute__((ext_vector_type(2))) __bf16 bf16x2v;
__device__ __forceinline__ bf16x4 exp_pack(f32x4 sc, float& lsum) {
    float e0 = EXP2(sc[0]), e1 = EXP2(sc[1]);
    float e2 = EXP2(sc[2]), e3 = EXP2(sc[3]);
    lsum += (e0 + e1) + (e2 + e3);
    union { bf16x2v v[2]; bf16x4 s; } u;
    u.v[0] = __builtin_amdgcn_cvt_pk_bf16_f32(e0, e1);
    u.v[1] = __builtin_amdgcn_cvt_pk_bf16_f32(e2, e3);
    return u.s;
}
#else
__device__ __forceinline__ bf16x4 exp_pack(f32x4 sc, float& lsum) {
    union { float f; unsigned int u; } e0, e1, e2, e3;
    e0.f = EXP2(sc[0]); e1.f = EXP2(sc[1]); e2.f = EXP2(sc[2]); e3.f = EXP2(sc[3]);
    unsigned int t0 = e0.u & 0xffff0000u, t1 = e1.u & 0xffff0000u;
    unsigned int t2 = e2.u & 0xffff0000u, t3 = e3.u & 0xffff0000u;
    lsum += (asf(t0) + asf(t1)) + (asf(t2) + asf(t3));
    union { unsigned int d[2]; bf16x4 v; } pk;
    pk.d[0] = (t0 >> 16) | t1;
    pk.d[1] = (t2 >> 16) | t3;
    return pk.v;
}
#endif

// One 128-key chunk. KU holds this chunk's K frags; KP gets next chunk's.
// V frags for THIS chunk issue first (consumed a QK/exp phase later).
#define CHUNK(C0, KU, KP)                                                      \
    {                                                                          \
        bf16x8 v[8];                                                           \
        _Pragma("unroll")                                                      \
        for (int q2 = 0; q2 < 4; ++q2) {                                       \
            v[q2 * 2]     = *(const bf16x8*)(vp0 + (C0) + q2 * 32);            \
            v[q2 * 2 + 1] = *(const bf16x8*)(vp1 + (C0) + q2 * 32);            \
        }                                                                      \
        const int pfb = ((C0) + 128) & 4095;                                   \
        _Pragma("unroll")                                                      \
        for (int s8 = 0; s8 < 8; ++s8)                                         \
            KP[s8] = *(const bf16x8*)(kfp + (size_t)(pfb + s8 * 16) * 32);     \
        _Pragma("unroll")                                                      \
        for (int sub = 0; sub < 2; ++sub) {                                    \
            _Pragma("unroll")                                                  \
            for (int s = 0; s < 4; ++s) {                                      \
                f32x4 sc = __builtin_amdgcn_mfma_f32_16x16x32_bf16(            \
                    KU[sub * 4 + s], qfrag, (f32x4){0.f, 0.f, 0.f, 0.f},       \
                    0, 0, 0);                                                  \
                bf16x4 pk = exp_pack(sc, lsum);                                \
                *(bf16x4*)(pw + l15 * PSTR + s * 16 + quad * 4) = pk;          \
            }                                                                  \
            _Pragma("unroll")                                                  \
            for (int ng = 0; ng < 2; ++ng) {                                   \
                bf16x8 pfrag = *(const bf16x8*)(pw + l15 * PSTR + ng * 32 +    \
                                                quad * 8);                     \
                const int q2 = sub * 2 + ng;                                   \
                acc0 = __builtin_amdgcn_mfma_f32_16x16x32_bf16(                \
                    v[q2 * 2], pfrag, acc0, 0, 0, 0);                          \
                acc1 = __builtin_amdgcn_mfma_f32_16x16x32_bf16(                \
                    v[q2 * 2 + 1], pfrag, acc1, 0, 0, 0);                      \
            }                                                                  \
        }                                                                      \
    }

__global__ __launch_bounds__(256, 3) void attn_kernel(
    const unsigned short* __restrict__ xqT,
    const unsigned short* __restrict__ xv,
    const float* __restrict__ points,
    float* __restrict__ z, float* __restrict__ pstats)
{
    __shared__ unsigned short Pl[4][16 * PSTR]; // per-wave P  9216 B

    const int bid = blockIdx.x;                 // 1024 blocks
    // XCD swizzle: XCD x = bid&7 gets heads {2x, 2x+1} (1MB K+V per L2).
    const int x  = bid & 7;
    const int r  = bid >> 3;          // 0..127
    const int h  = x * 2 + (r & 1);
    const int qt = r >> 1;            // 0..63
    const int b = h >> 3, g = h & 7;
    const int tid = threadIdx.x;
    const int wv = tid >> 6, lane = tid & 63;
    const int quad = lane >> 4, l15 = lane & 15;

    const int m = qt * 64 + wv * 16 + l15;      // this lane's query col

    const unsigned short* kbase = xqT + (size_t)h * 4096 * 32;
    const unsigned short* vbase = xv  + (size_t)h * 32 * 4096;

    // Q fragment (B-operand): col=l15, k=quad*8+j
    const bf16x8 qfrag = *(const bf16x8*)(kbase + (size_t)m * 32 + quad * 8);

    f32x4 acc0 = {0.f, 0.f, 0.f, 0.f};   // O rows i = 0..15
    f32x4 acc1 = {0.f, 0.f, 0.f, 0.f};   // O rows i = 16..31
    float lsum = 0.f;

    unsigned short* pw = &Pl[wv][0];

    // per-lane fragment bases
    const unsigned short* kfp = kbase + (size_t)l15 * 32 + quad * 8;
    const unsigned short* vp0 = vbase + (size_t)l15 * 4096 + quad * 8;
    const unsigned short* vp1 = vbase + (size_t)(16 + l15) * 4096 + quad * 8;

    // K prefetch: chunk 0 into kA
    bf16x8 kA[8], kB[8];
#pragma unroll
    for (int s8 = 0; s8 < 8; ++s8)
        kA[s8] = *(const bf16x8*)(kfp + (size_t)(s8 * 16) * 32);

    for (int n0 = 0; n0 < 4096; n0 += 256) {
        CHUNK(n0,       kA, kB);
        CHUNK(n0 + 128, kB, kA);
    }

    // denominator: sum partial l over the 4 quads sharing column m
    lsum += __shfl_xor(lsum, 16, 64);
    lsum += __shfl_xor(lsum, 32, 64);
    const float inv = 1.f / lsum;

    const float* pb = points + (size_t)b * 256 * 4096;
    float* zb = z + (size_t)b * 256 * 4096;
    float* sb = pstats + ((size_t)bid * 4 + wv) * 64;   // private slot

#pragma unroll
    for (int half = 0; half < 2; ++half) {
        f32x4 a = half ? acc1 : acc0;
#pragma unroll
        for (int rr = 0; rr < 4; ++rr) {
            const int i = half * 16 + quad * 4 + rr;       // C/D row; gn group
            const size_t off = (size_t)(i * 8 + g) * 4096; // channel shuffle
            float zA = a[rr] * inv + pb[off + m];
            zb[off + m] = zA;
            // GN partial sums over this wave's 16 query columns (no atomics)
            float s  = zA;
            float ss = zA * zA;
            s += __shfl_xor(s, 1, 64);  ss += __shfl_xor(ss, 1, 64);
            s += __shfl_xor(s, 2, 64);  ss += __shfl_xor(ss, 2, 64);
            s += __shfl_xor(s, 4, 64);  ss += __shfl_xor(ss, 4, 64);
            s += __shfl_xor(s, 8, 64);  ss += __shfl_xor(ss, 8, 64);
            if (l15 == 0) {
                sb[i * 2]     = s;
                sb[i * 2 + 1] = ss;
            }
        }
    }
}

// ---------------------------------------------------------------------------
// Kernel 3: combine GN partials. 64 blocks = (b, gn group i).
// pstats slot = bid*4 + wv; batch(bid) = (bid>>2)&1. 512 bids per batch.
// ---------------------------------------------------------------------------
__global__ __launch_bounds__(256) void gn_combine(const float* __restrict__ pstats,
                                                  float* __restrict__ stats)
{
    const int b = blockIdx.x >> 5;          // batch
    const int i = blockIdx.x & 31;          // gn group
    const int tid = threadIdx.x;
    float s = 0.f, ss = 0.f;
    for (int k = tid; k < 2048; k += 256) { // 512 bids x 4 waves
        const int wvk = k & 3, j = k >> 2;  // j in [0,512)
        const int bid = (j & 3) | (b << 2) | ((j >> 2) << 3);
        const float* p = pstats + ((size_t)bid * 4 + wvk) * 64 + i * 2;
        s += p[0]; ss += p[1];
    }
#pragma unroll
    for (int off = 32; off > 0; off >>= 1) {
        s  += __shfl_down(s, off, 64);
        ss += __shfl_down(ss, off, 64);
    }
    __shared__ float red[8];
    const int w = tid >> 6;
    if ((tid & 63) == 0) { red[w * 2] = s; red[w * 2 + 1] = ss; }
    __syncthreads();
    if (tid == 0) {
        s  = red[0] + red[2] + red[4] + red[6];
        ss = red[1] + red[3] + red[5] + red[7];
        float mean = s * (1.f / 32768.f);
        float var  = ss * (1.f / 32768.f) - mean * mean;
        stats[blockIdx.x * 2]     = mean;
        stats[blockIdx.x * 2 + 1] = rsqrtf(var + 1e-5f);
    }
}

// ---------------------------------------------------------------------------
// Kernel 4: GroupNorm apply, in place on d_out.
// ---------------------------------------------------------------------------
__global__ __launch_bounds__(256) void gn_apply(float* __restrict__ z,
                                                const float* __restrict__ stats,
                                                const float* __restrict__ gw,
                                                const float* __restrict__ gb)
{
    const int idx = blockIdx.x * 256 + threadIdx.x;  // float4 index
    float4* p = (float4*)z;
    float4 v = p[idx];
    const int chg = idx >> 10;       // global channel b*256+ch
    const int blk = chg >> 3;        // stats slot = b*32 + ch/8
    const int ch  = chg & 255;
    const float mean = stats[blk * 2], rstd = stats[blk * 2 + 1];
    const float w  = gw[ch] * rstd;
    const float bb = gb[ch] - mean * w;
    v.x = v.x * w + bb; v.y = v.y * w + bb;
    v.z = v.z * w + bb; v.w = v.w * w + bb;
    p[idx] = v;
}

extern "C" void kernel_launch(void* const* d_in, const int* in_sizes, int n_in,
                              void* d_out, int out_size, void* d_ws, size_t ws_size,
                              hipStream_t stream)
{
    const float* points = (const float*)d_in[0];
    const float* conv_w = (const float*)d_in[1];
    const float* conv_b = (const float*)d_in[2];
    const float* gn_w   = (const float*)d_in[3];
    const float* gn_b   = (const float*)d_in[4];
    float* out = (float*)d_out;
    char* ws = (char*)d_ws;
    const size_t MB = 1024 * 1024;
    unsigned short* xqT = (unsigned short*)ws;                   // 0..4 MB
    unsigned short* xv  = (unsigned short*)(ws + 4 * MB);        // 4..8 MB
    float* pstats = (float*)(ws + 8 * MB);                       // 1 MB
    float* stats  = (float*)(ws + 9 * MB);                       // 512 B

    conv_kernel<<<1024, 256, 0, stream>>>(points, conv_w, conv_b, xqT, xv);
    attn_kernel<<<1024, 256, 0, stream>>>(xqT, xv, points, out, pstats);
    gn_combine<<<64, 256, 0, stream>>>(pstats, stats);
    gn_apply<<<2048, 256, 0, stream>>>(out, stats, gn_w, gn_b);
}

// Round 13
// 174.848 us; speedup vs baseline: 1.4591x; 1.4591x over previous
//
#include <hip/hip_runtime.h>

typedef __attribute__((ext_vector_type(8))) short bf16x8;
typedef __attribute__((ext_vector_type(4))) short bf16x4;
typedef __attribute__((ext_vector_type(4))) float f32x4;

#if __has_builtin(__builtin_amdgcn_exp2f)
#define EXP2(x) __builtin_amdgcn_exp2f(x)
#else
#define EXP2(x) exp2f(x)
#endif

__device__ __forceinline__ unsigned short f2bf(float f) {
    union { float f; unsigned int u; } v; v.f = f;
    unsigned int r = v.u + 0x7fffu + ((v.u >> 16) & 1u);
    return (unsigned short)(r >> 16);
}

__device__ __forceinline__ float asf(unsigned int u) {
    union { unsigned int u; float f; } v; v.u = u; return v.f;
}

// sqrt( (1/sqrt(32)) * log2(e) ) — baked into BOTH xqT operands so QK^T
// emerges pre-multiplied by scale*log2e: exp2(raw score) == softmax numerator.
#define QK_PRESCALE 0.50500983f

// ---------------------------------------------------------------------------
// Kernel 1: grouped 1x1 conv, 1024 blocks (R9-measured).
// ---------------------------------------------------------------------------
__global__ __launch_bounds__(256) void conv_kernel(
    const float* __restrict__ points, const float* __restrict__ conv_w,
    const float* __restrict__ conv_b,
    unsigned short* __restrict__ xqT, unsigned short* __restrict__ xv)
{
    __shared__ float w[1024];
    const int h  = blockIdx.x >> 6;   // 16 heads
    const int nc = blockIdx.x & 63;   // 64 n-chunks of 64
    const int g  = h & 7;
    const int tid = threadIdx.x;
    const float* wg = conv_w + g * 1024;
    for (int k = tid; k < 1024; k += 256) w[k] = wg[k];
    __syncthreads();
    const int n  = nc * 64 + (tid & 63);
    const int ig = tid >> 6;          // wave id -> channels [ig*8, ig*8+8)
    const float* p = points + (size_t)h * 32 * 4096 + n;
    float pv[32];
#pragma unroll
    for (int j = 0; j < 32; ++j) pv[j] = p[(size_t)j * 4096];
    float out[8];
#pragma unroll
    for (int ii = 0; ii < 8; ++ii) {
        const int i = ig * 8 + ii;
        float acc = conv_b[g * 32 + i];
        const float4* w4 = (const float4*)(w + i * 32);   // ds_read_b128
#pragma unroll
        for (int j4 = 0; j4 < 8; ++j4) {
            float4 ww = w4[j4];
            acc += ww.x * pv[j4 * 4]     + ww.y * pv[j4 * 4 + 1]
                 + ww.z * pv[j4 * 4 + 2] + ww.w * pv[j4 * 4 + 3];
        }
        out[ii] = acc;
    }
    unsigned short tq[8];
#pragma unroll
    for (int ii = 0; ii < 8; ++ii) tq[ii] = f2bf(out[ii] * QK_PRESCALE);
    *(bf16x8*)(xqT + ((size_t)h * 4096 + n) * 32 + ig * 8) = *(bf16x8*)tq;
#pragma unroll
    for (int ii = 0; ii < 8; ++ii) {
        float x = out[ii];
        float e = x > 0.f ? x : (__expf(x) - 1.f);   // elu
        xv[((size_t)h * 32 + ig * 8 + ii) * 4096 + n] = f2bf(e);
    }
}

// ---------------------------------------------------------------------------
// Kernel 2: flash attention, 128 QUERIES/BLOCK + KEY-SPLIT (grid stays 1024
// = 4 blocks/CU). Per block: 128 q x 2048 keys. K+V staged in LDS per block
// (R7: 128-key chunks, 2 barriers, register prefetch across the barrier);
// 2 Q-fragments per wave. Halves per-head K/V re-reads vs R7/R9 — attacking
// the L2-traffic term that the 87us plateau tracked. Unnormalized O + lsum
// partials out; combine kernel merges key-halves (R11-proven).
// ---------------------------------------------------------------------------
#define KSTR 40    // 32 + 8 pad shorts
#define VSTR 136   // 128 + 8 pad shorts
#define PSTR 72    // 64 + 8 pad shorts

#if __has_builtin(__builtin_amdgcn_cvt_pk_bf16_f32)
typedef __attribute__((ext_vector_type(2))) __bf16 bf16x2v;
__device__ __forceinline__ bf16x4 exp_pack(f32x4 sc, float& lsum) {
    float e0 = EXP2(sc[0]), e1 = EXP2(sc[1]);
    float e2 = EXP2(sc[2]), e3 = EXP2(sc[3]);
    lsum += (e0 + e1) + (e2 + e3);
    union { bf16x2v v[2]; bf16x4 s; } u;
    u.v[0] = __builtin_amdgcn_cvt_pk_bf16_f32(e0, e1);
    u.v[1] = __builtin_amdgcn_cvt_pk_bf16_f32(e2, e3);
    return u.s;
}
#else
__device__ __forceinline__ bf16x4 exp_pack(f32x4 sc, float& lsum) {
    union { float f; unsigned int u; } e0, e1, e2, e3;
    e0.f = EXP2(sc[0]); e1.f = EXP2(sc[1]); e2.f = EXP2(sc[2]); e3.f = EXP2(sc[3]);
    unsigned int t0 = e0.u & 0xffff0000u, t1 = e1.u & 0xffff0000u;
    unsigned int t2 = e2.u & 0xffff0000u, t3 = e3.u & 0xffff0000u;
    lsum += (asf(t0) + asf(t1)) + (asf(t2) + asf(t3));
    union { unsigned int d[2]; bf16x4 v; } pk;
    pk.d[0] = (t0 >> 16) | t1;
    pk.d[1] = (t2 >> 16) | t3;
    return pk.v;
}
#endif

__global__ __launch_bounds__(256, 4) void attn_kernel(
    const unsigned short* __restrict__ xqT,
    const unsigned short* __restrict__ xv,
    float* __restrict__ opart, float* __restrict__ lpart)
{
    __shared__ unsigned short Kt[128 * KSTR];     // [n][i]    10240 B
    __shared__ unsigned short Vt[32 * VSTR];      // [i][n]     8704 B
    __shared__ unsigned short Pl[4][32 * PSTR];   // per-wave  18432 B

    const int bid = blockIdx.x;                   // 1024 blocks
    // XCD swizzle: XCD x = bid&7 gets heads {2x, 2x+1}.
    const int x  = bid & 7;
    const int r  = bid >> 3;          // 0..127
    const int h  = x * 2 + (r & 1);
    const int rr = r >> 1;            // 0..63
    const int qt = rr & 31;           // 32 query tiles of 128
    const int kh = rr >> 5;           // key half
    const int tid = threadIdx.x;
    const int wv = tid >> 6, lane = tid & 63;
    const int quad = lane >> 4, l15 = lane & 15;

    const int mA = qt * 128 + wv * 32 + l15;      // query cols (two frags)
    const int mB = mA + 16;

    const unsigned short* kbase  = xqT + (size_t)h * 4096 * 32;
    const unsigned short* khalf  = kbase + (size_t)kh * 2048 * 32;
    const unsigned short* vbaseh = xv + (size_t)h * 32 * 4096 + kh * 2048;

    // Q fragments (B-operand): col=l15, k=quad*8+j
    const bf16x8 qfragA = *(const bf16x8*)(kbase + (size_t)mA * 32 + quad * 8);
    const bf16x8 qfragB = *(const bf16x8*)(kbase + (size_t)mB * 32 + quad * 8);

    f32x4 accA0 = {0,0,0,0}, accA1 = {0,0,0,0};
    f32x4 accB0 = {0,0,0,0}, accB1 = {0,0,0,0};
    float lsumA = 0.f, lsumB = 0.f;

    const int kr = tid >> 2, kc = (tid & 3) * 8;   // K staging [n][i], 2 rows
    const int vi = tid >> 3, vn = (tid & 7) * 8;   // V staging [i][n], 2 cols
    unsigned short* pw = &Pl[wv][0];

    // register prefetch: chunk 0
    bf16x8 ka = *(const bf16x8*)(khalf + (size_t)kr * 32 + kc);
    bf16x8 kb = *(const bf16x8*)(khalf + (size_t)(64 + kr) * 32 + kc);
    bf16x8 va = *(const bf16x8*)(vbaseh + (size_t)vi * 4096 + vn);
    bf16x8 vb = *(const bf16x8*)(vbaseh + (size_t)vi * 4096 + vn + 64);

    for (int n0 = 0; n0 < 2048; n0 += 128) {
        __syncthreads();
        *(bf16x8*)(Kt + kr * KSTR + kc)        = ka;
        *(bf16x8*)(Kt + (kr + 64) * KSTR + kc) = kb;
        *(bf16x8*)(Vt + vi * VSTR + vn)        = va;
        *(bf16x8*)(Vt + vi * VSTR + vn + 64)   = vb;
        __syncthreads();
        const int pfb = (n0 + 128) & 2047;   // wraps to 0 on last (harmless)
        ka = *(const bf16x8*)(khalf + (size_t)(pfb + kr) * 32 + kc);
        kb = *(const bf16x8*)(khalf + (size_t)(pfb + 64 + kr) * 32 + kc);
        va = *(const bf16x8*)(vbaseh + (size_t)vi * 4096 + pfb + vn);
        vb = *(const bf16x8*)(vbaseh + (size_t)vi * 4096 + pfb + vn + 64);

#pragma unroll
        for (int sub = 0; sub < 2; ++sub) {
#pragma unroll
            for (int s = 0; s < 4; ++s) {
                // A-operand K^T: A[r=n][k=i], lane r=l15
                bf16x8 kf = *(const bf16x8*)(
                    Kt + (sub * 64 + s * 16 + l15) * KSTR + quad * 8);
                f32x4 scA = __builtin_amdgcn_mfma_f32_16x16x32_bf16(
                    kf, qfragA, (f32x4){0,0,0,0}, 0, 0, 0);
                f32x4 scB = __builtin_amdgcn_mfma_f32_16x16x32_bf16(
                    kf, qfragB, (f32x4){0,0,0,0}, 0, 0, 0);
                bf16x4 pkA = exp_pack(scA, lsumA);
                bf16x4 pkB = exp_pack(scB, lsumB);
                *(bf16x4*)(pw + l15 * PSTR + s * 16 + quad * 4) = pkA;
                *(bf16x4*)(pw + (16 + l15) * PSTR + s * 16 + quad * 4) = pkB;
            }
#pragma unroll
            for (int ng = 0; ng < 2; ++ng) {
                bf16x8 pfA = *(const bf16x8*)(pw + l15 * PSTR + ng * 32 + quad * 8);
                bf16x8 pfB = *(const bf16x8*)(pw + (16 + l15) * PSTR + ng * 32 + quad * 8);
                const int col = sub * 64 + ng * 32 + quad * 8;
                bf16x8 v0 = *(const bf16x8*)(Vt + l15 * VSTR + col);
                bf16x8 v1 = *(const bf16x8*)(Vt + (16 + l15) * VSTR + col);
                accA0 = __builtin_amdgcn_mfma_f32_16x16x32_bf16(v0, pfA, accA0, 0, 0, 0);
                accA1 = __builtin_amdgcn_mfma_f32_16x16x32_bf16(v1, pfA, accA1, 0, 0, 0);
                accB0 = __builtin_amdgcn_mfma_f32_16x16x32_bf16(v0, pfB, accB0, 0, 0, 0);
                accB1 = __builtin_amdgcn_mfma_f32_16x16x32_bf16(v1, pfB, accB1, 0, 0, 0);
            }
        }
    }

    // partial denominators across the 4 quads sharing each query column
    lsumA += __shfl_xor(lsumA, 16, 64);  lsumA += __shfl_xor(lsumA, 32, 64);
    lsumB += __shfl_xor(lsumB, 16, 64);  lsumB += __shfl_xor(lsumB, 32, 64);

    // write UNNORMALIZED partials: opart[slot][32 i][128 m]
    const size_t slot = (((size_t)h * 32 + qt) * 2 + kh);
    float* ob = opart + slot * 4096;
    const int mlA = wv * 32 + l15, mlB = mlA + 16;
#pragma unroll
    for (int half = 0; half < 2; ++half) {
        f32x4 aA = half ? accA1 : accA0;
        f32x4 aB = half ? accB1 : accB0;
#pragma unroll
        for (int r2 = 0; r2 < 4; ++r2) {
            const int i = half * 16 + quad * 4 + r2;
            ob[i * 128 + mlA] = aA[r2];
            ob[i * 128 + mlB] = aB[r2];
        }
    }
    if (quad == 0) {
        lpart[slot * 128 + mlA] = lsumA;
        lpart[slot * 128 + mlB] = lsumB;
    }
}

// ---------------------------------------------------------------------------
// Kernel 3: combine key-halves. 512 blocks = (h, qt). Merge O/l partials,
// normalize, channel shuffle, +residual, write z, emit private GN partials.
// ---------------------------------------------------------------------------
__global__ __launch_bounds__(256) void combine_kernel(
    const float* __restrict__ opart, const float* __restrict__ lpart,
    const float* __restrict__ points, float* __restrict__ z,
    float* __restrict__ pstats)
{
    const int bid2 = blockIdx.x;      // (h, qt)
    const int h = bid2 >> 5, qt = bid2 & 31;
    const int b = h >> 3, g = h & 7;
    const int tid = threadIdx.x;
    const int w = tid >> 6, lane = tid & 63;

    const size_t sl0 = (size_t)bid2 * 2;   // kh=0 slot; kh=1 is sl0+1
    const float inv0 = 1.f / (lpart[sl0 * 128 + lane] +
                              lpart[(sl0 + 1) * 128 + lane]);
    const float inv1 = 1.f / (lpart[sl0 * 128 + 64 + lane] +
                              lpart[(sl0 + 1) * 128 + 64 + lane]);

    const float* oa  = opart + sl0 * 4096;
    const float* obp = opart + (sl0 + 1) * 4096;
    const float* pb = points + (size_t)b * 256 * 4096;
    float* zb = z + (size_t)b * 256 * 4096;
    float* sb = pstats + (size_t)bid2 * 64;
    const int mg0 = qt * 128 + lane, mg1 = mg0 + 64;

#pragma unroll
    for (int ii = 0; ii < 8; ++ii) {
        const int i = w * 8 + ii;                      // gn group
        const size_t off = (size_t)(i * 8 + g) * 4096; // channel shuffle
        float v0 = (oa[i * 128 + lane]      + obp[i * 128 + lane])      * inv0 + pb[off + mg0];
        float v1 = (oa[i * 128 + 64 + lane] + obp[i * 128 + 64 + lane]) * inv1 + pb[off + mg1];
        zb[off + mg0] = v0;
        zb[off + mg1] = v1;
        float s = v0 + v1, ss = v0 * v0 + v1 * v1;
        s += __shfl_xor(s, 1, 64);   ss += __shfl_xor(ss, 1, 64);
        s += __shfl_xor(s, 2, 64);   ss += __shfl_xor(ss, 2, 64);
        s += __shfl_xor(s, 4, 64);   ss += __shfl_xor(ss, 4, 64);
        s += __shfl_xor(s, 8, 64);   ss += __shfl_xor(ss, 8, 64);
        s += __shfl_xor(s, 16, 64);  ss += __shfl_xor(ss, 16, 64);
        s += __shfl_xor(s, 32, 64);  ss += __shfl_xor(ss, 32, 64);
        if (lane == 0) { sb[i * 2] = s; sb[i * 2 + 1] = ss; }
    }
}

// ---------------------------------------------------------------------------
// Kernel 4: combine GN partials. 64 blocks = (b, gn group i); 256 slots each.
// ---------------------------------------------------------------------------
__global__ __launch_bounds__(256) void gn_combine(const float* __restrict__ pstats,
                                                  float* __restrict__ stats)
{
    const int b = blockIdx.x >> 5;
    const int i = blockIdx.x & 31;
    const int tid = threadIdx.x;
    const float* p = pstats + (size_t)(b * 256 + tid) * 64 + i * 2;
    float s = p[0], ss = p[1];      // exactly 256 slots, one per thread
#pragma unroll
    for (int off = 32; off > 0; off >>= 1) {
        s  += __shfl_down(s, off, 64);
        ss += __shfl_down(ss, off, 64);
    }
    __shared__ float red[8];
    const int w = tid >> 6;
    if ((tid & 63) == 0) { red[w * 2] = s; red[w * 2 + 1] = ss; }
    __syncthreads();
    if (tid == 0) {
        s  = red[0] + red[2] + red[4] + red[6];
        ss = red[1] + red[3] + red[5] + red[7];
        float mean = s * (1.f / 32768.f);
        float var  = ss * (1.f / 32768.f) - mean * mean;
        stats[blockIdx.x * 2]     = mean;
        stats[blockIdx.x * 2 + 1] = rsqrtf(var + 1e-5f);
    }
}

// ---------------------------------------------------------------------------
// Kernel 5: GroupNorm apply, in place on d_out.
// ---------------------------------------------------------------------------
__global__ __launch_bounds__(256) void gn_apply(float* __restrict__ z,
                                                const float* __restrict__ stats,
                                                const float* __restrict__ gw,
                                                const float* __restrict__ gb)
{
    const int idx = blockIdx.x * 256 + threadIdx.x;  // float4 index
    float4* p = (float4*)z;
    float4 v = p[idx];
    const int chg = idx >> 10;       // global channel b*256+ch
    const int blk = chg >> 3;        // stats slot = b*32 + ch/8
    const int ch  = chg & 255;
    const float mean = stats[blk * 2], rstd = stats[blk * 2 + 1];
    const float w  = gw[ch] * rstd;
    const float bb = gb[ch] - mean * w;
    v.x = v.x * w + bb; v.y = v.y * w + bb;
    v.z = v.z * w + bb; v.w = v.w * w + bb;
    p[idx] = v;
}

extern "C" void kernel_launch(void* const* d_in, const int* in_sizes, int n_in,
                              void* d_out, int out_size, void* d_ws, size_t ws_size,
                              hipStream_t stream)
{
    const float* points = (const float*)d_in[0];
    const float* conv_w = (const float*)d_in[1];
    const float* conv_b = (const float*)d_in[2];
    const float* gn_w   = (const float*)d_in[3];
    const float* gn_b   = (const float*)d_in[4];
    float* out = (float*)d_out;
    char* ws = (char*)d_ws;
    const size_t MB = 1024 * 1024;
    unsigned short* xqT = (unsigned short*)ws;                   // 0..4 MB
    unsigned short* xv  = (unsigned short*)(ws + 4 * MB);        // 4..8 MB
    float* opart  = (float*)(ws + 8 * MB);                       // 16 MB
    float* lpart  = (float*)(ws + 24 * MB);                      // 512 KB
    float* pstats = (float*)(ws + 25 * MB);                      // 128 KB
    float* stats  = (float*)(ws + 26 * MB);                      // 512 B

    conv_kernel<<<1024, 256, 0, stream>>>(points, conv_w, conv_b, xqT, xv);
    attn_kernel<<<1024, 256, 0, stream>>>(xqT, xv, opart, lpart);
    combine_kernel<<<512, 256, 0, stream>>>(opart, lpart, points, out, pstats);
    gn_combine<<<64, 256, 0, stream>>>(pstats, stats);
    gn_apply<<<2048, 256, 0, stream>>>(out, stats, gn_w, gn_b);
}

// Round 14
// 163.964 us; speedup vs baseline: 1.5559x; 1.0664x over previous
//
#include <hip/hip_runtime.h>

typedef __attribute__((ext_vector_type(8))) short bf16x8;
typedef __attribute__((ext_vector_type(4))) short bf16x4;
typedef __attribute__((ext_vector_type(4))) float f32x4;

#if __has_builtin(__builtin_amdgcn_exp2f)
#define EXP2(x) __builtin_amdgcn_exp2f(x)
#else
#define EXP2(x) exp2f(x)
#endif

__device__ __forceinline__ unsigned short f2bf(float f) {
    union { float f; unsigned int u; } v; v.f = f;
    unsigned int r = v.u + 0x7fffu + ((v.u >> 16) & 1u);
    return (unsigned short)(r >> 16);
}

__device__ __forceinline__ float asf(unsigned int u) {
    union { unsigned int u; float f; } v; v.u = u; return v.f;
}

// sqrt( (1/sqrt(32)) * log2(e) ) — baked into BOTH xqT operands so QK^T
// emerges pre-multiplied by scale*log2e: exp2(raw score) == softmax numerator.
#define QK_PRESCALE 0.50500983f

// ---------------------------------------------------------------------------
// Kernel 1: grouped 1x1 conv, 1024 blocks (R9-measured, unchanged).
// ---------------------------------------------------------------------------
__global__ __launch_bounds__(256) void conv_kernel(
    const float* __restrict__ points, const float* __restrict__ conv_w,
    const float* __restrict__ conv_b,
    unsigned short* __restrict__ xqT, unsigned short* __restrict__ xv)
{
    __shared__ float w[1024];
    const int h  = blockIdx.x >> 6;   // 16 heads
    const int nc = blockIdx.x & 63;   // 64 n-chunks of 64
    const int g  = h & 7;
    const int tid = threadIdx.x;
    const float* wg = conv_w + g * 1024;
    for (int k = tid; k < 1024; k += 256) w[k] = wg[k];
    __syncthreads();
    const int n  = nc * 64 + (tid & 63);
    const int ig = tid >> 6;          // wave id -> channels [ig*8, ig*8+8)
    const float* p = points + (size_t)h * 32 * 4096 + n;
    float pv[32];
#pragma unroll
    for (int j = 0; j < 32; ++j) pv[j] = p[(size_t)j * 4096];
    float out[8];
#pragma unroll
    for (int ii = 0; ii < 8; ++ii) {
        const int i = ig * 8 + ii;
        float acc = conv_b[g * 32 + i];
        const float4* w4 = (const float4*)(w + i * 32);   // ds_read_b128
#pragma unroll
        for (int j4 = 0; j4 < 8; ++j4) {
            float4 ww = w4[j4];
            acc += ww.x * pv[j4 * 4]     + ww.y * pv[j4 * 4 + 1]
                 + ww.z * pv[j4 * 4 + 2] + ww.w * pv[j4 * 4 + 3];
        }
        out[ii] = acc;
    }
    unsigned short tq[8];
#pragma unroll
    for (int ii = 0; ii < 8; ++ii) tq[ii] = f2bf(out[ii] * QK_PRESCALE);
    *(bf16x8*)(xqT + ((size_t)h * 4096 + n) * 32 + ig * 8) = *(bf16x8*)tq;
#pragma unroll
    for (int ii = 0; ii < 8; ++ii) {
        float x = out[ii];
        float e = x > 0.f ? x : (__expf(x) - 1.f);   // elu
        xv[((size_t)h * 32 + ig * 8 + ii) * 4096 + n] = f2bf(e);
    }
}

// ---------------------------------------------------------------------------
// Kernel 2: flash attention — R9 loop VERBATIM (measured floor 87.3us across
// R7-R13; every peripheral diet was neutral). Only addition: epilogue emits
// per-(block,wave) GroupNorm partial sums to PRIVATE pstats slots (no
// atomics, no barrier) so the separate gn_stats pass (8MB re-read) dies.
// ---------------------------------------------------------------------------
#define VSTR 136   // 128 + 8 pad shorts
#define PSTR 72    // 64 + 8 pad shorts

#if __has_builtin(__builtin_amdgcn_cvt_pk_bf16_f32)
typedef __attribute__((ext_vector_type(2))) __bf16 bf16x2v;
__device__ __forceinline__ bf16x4 exp_pack(f32x4 sc, float& lsum) {
    float e0 = EXP2(sc[0]), e1 = EXP2(sc[1]);
    float e2 = EXP2(sc[2]), e3 = EXP2(sc[3]);
    lsum += (e0 + e1) + (e2 + e3);
    union { bf16x2v v[2]; bf16x4 s; } u;
    u.v[0] = __builtin_amdgcn_cvt_pk_bf16_f32(e0, e1);
    u.v[1] = __builtin_amdgcn_cvt_pk_bf16_f32(e2, e3);
    return u.s;
}
#else
__device__ __forceinline__ bf16x4 exp_pack(f32x4 sc, float& lsum) {
    union { float f; unsigned int u; } e0, e1, e2, e3;
    e0.f = EXP2(sc[0]); e1.f = EXP2(sc[1]); e2.f = EXP2(sc[2]); e3.f = EXP2(sc[3]);
    unsigned int t0 = e0.u & 0xffff0000u, t1 = e1.u & 0xffff0000u;
    unsigned int t2 = e2.u & 0xffff0000u, t3 = e3.u & 0xffff0000u;
    lsum += (asf(t0) + asf(t1)) + (asf(t2) + asf(t3));
    union { unsigned int d[2]; bf16x4 v; } pk;
    pk.d[0] = (t0 >> 16) | t1;
    pk.d[1] = (t2 >> 16) | t3;
    return pk.v;
}
#endif

// One 128-key chunk (R9): stage V, prefetch next V (regs) + next K frags
// (KP), compute 8 x 16-key steps from current K frags (KU). pfb wraps on
// the last chunk (harmless valid-memory prefetch, no branch).
#define CHUNK(C0, KU, KP)                                                      \
    {                                                                          \
        __syncthreads();                                                       \
        *(bf16x8*)(Vt + vi * VSTR + vn)      = va;                             \
        *(bf16x8*)(Vt + vi * VSTR + vn + 64) = vb;                             \
        __syncthreads();                                                       \
        const int pfb = ((C0) + 128) & 4095;                                   \
        va = *(const bf16x8*)(vbase + (size_t)vi * 4096 + pfb + vn);           \
        vb = *(const bf16x8*)(vbase + (size_t)vi * 4096 + pfb + vn + 64);      \
        _Pragma("unroll")                                                      \
        for (int s8 = 0; s8 < 8; ++s8)                                         \
            KP[s8] = *(const bf16x8*)(kfp + (size_t)(pfb + s8 * 16) * 32);     \
        _Pragma("unroll")                                                      \
        for (int sub = 0; sub < 2; ++sub) {                                    \
            _Pragma("unroll")                                                  \
            for (int s = 0; s < 4; ++s) {                                      \
                f32x4 sc = __builtin_amdgcn_mfma_f32_16x16x32_bf16(            \
                    KU[sub * 4 + s], qfrag, (f32x4){0.f, 0.f, 0.f, 0.f},       \
                    0, 0, 0);                                                  \
                bf16x4 pk = exp_pack(sc, lsum);                                \
                *(bf16x4*)(pw + l15 * PSTR + s * 16 + quad * 4) = pk;          \
            }                                                                  \
            _Pragma("unroll")                                                  \
            for (int ng = 0; ng < 2; ++ng) {                                   \
                bf16x8 pfrag = *(const bf16x8*)(pw + l15 * PSTR + ng * 32 +    \
                                                quad * 8);                     \
                const int col = sub * 64 + ng * 32 + quad * 8;                 \
                bf16x8 v0 = *(const bf16x8*)(Vt + l15 * VSTR + col);           \
                bf16x8 v1 = *(const bf16x8*)(Vt + (16 + l15) * VSTR + col);    \
                acc0 = __builtin_amdgcn_mfma_f32_16x16x32_bf16(v0, pfrag,      \
                                                               acc0, 0, 0, 0); \
                acc1 = __builtin_amdgcn_mfma_f32_16x16x32_bf16(v1, pfrag,      \
                                                               acc1, 0, 0, 0); \
            }                                                                  \
        }                                                                      \
    }

__global__ __launch_bounds__(256, 4) void attn_kernel(
    const unsigned short* __restrict__ xqT,
    const unsigned short* __restrict__ xv,
    const float* __restrict__ points,
    float* __restrict__ z, float* __restrict__ pstats)
{
    __shared__ unsigned short Vt[32 * VSTR];    // [i][n]    8704 B
    __shared__ unsigned short Pl[4][16 * PSTR]; // per-wave  9216 B

    const int qt = blockIdx.x;        // 64 query tiles
    const int h  = blockIdx.y;        // 16 heads
    const int b = h >> 3, g = h & 7;
    const int tid = threadIdx.x;
    const int wv = tid >> 6, lane = tid & 63;
    const int quad = lane >> 4, l15 = lane & 15;

    const int m = qt * 64 + wv * 16 + l15;      // this lane's query col

    const unsigned short* kbase = xqT + (size_t)h * 4096 * 32;
    const unsigned short* vbase = xv  + (size_t)h * 32 * 4096;

    // Q fragment (B-operand): col=l15, k=quad*8+j
    const bf16x8 qfrag = *(const bf16x8*)(kbase + (size_t)m * 32 + quad * 8);

    f32x4 acc0 = {0.f, 0.f, 0.f, 0.f};   // O rows i = 0..15
    f32x4 acc1 = {0.f, 0.f, 0.f, 0.f};   // O rows i = 16..31
    float lsum = 0.f;

    const int vi = tid >> 3, vn = (tid & 7) * 8;   // V staging: [i][n], 2 cols
    unsigned short* pw = &Pl[wv][0];

    // per-lane K-fragment base (A-operand K^T): row l15, cols quad*8..+8
    const unsigned short* kfp = kbase + (size_t)l15 * 32 + quad * 8;

    // V staging prefetch regs (chunk 0)
    bf16x8 va = *(const bf16x8*)(vbase + (size_t)vi * 4096 + vn);
    bf16x8 vb = *(const bf16x8*)(vbase + (size_t)vi * 4096 + vn + 64);

    // K fragment double buffer (chunk 0 into kA)
    bf16x8 kA[8], kB[8];
#pragma unroll
    for (int s8 = 0; s8 < 8; ++s8)
        kA[s8] = *(const bf16x8*)(kfp + (size_t)(s8 * 16) * 32);

    for (int n0 = 0; n0 < 4096; n0 += 256) {
        CHUNK(n0,       kA, kB);
        CHUNK(n0 + 128, kB, kA);
    }

    // denominator: sum partial l over the 4 quads sharing column m
    lsum += __shfl_xor(lsum, 16, 64);
    lsum += __shfl_xor(lsum, 32, 64);
    const float inv = 1.f / lsum;

    const float* pb = points + (size_t)b * 256 * 4096;
    float* zb = z + (size_t)b * 256 * 4096;
    float* sb = pstats + (((size_t)h * 64 + qt) * 4 + wv) * 64;  // private

#pragma unroll
    for (int half = 0; half < 2; ++half) {
        f32x4 a = half ? acc1 : acc0;
#pragma unroll
        for (int r = 0; r < 4; ++r) {
            const int i = half * 16 + quad * 4 + r;       // C/D row; gn group
            const size_t off = (size_t)(i * 8 + g) * 4096;// channel shuffle
            float zA = a[r] * inv + pb[off + m];
            zb[off + m] = zA;
            // GN partial sums over this wave's 16 query columns (no atomics)
            float s  = zA;
            float ss = zA * zA;
            s += __shfl_xor(s, 1, 64);  ss += __shfl_xor(ss, 1, 64);
            s += __shfl_xor(s, 2, 64);  ss += __shfl_xor(ss, 2, 64);
            s += __shfl_xor(s, 4, 64);  ss += __shfl_xor(ss, 4, 64);
            s += __shfl_xor(s, 8, 64);  ss += __shfl_xor(ss, 8, 64);
            if (l15 == 0) {
                sb[i * 2]     = s;
                sb[i * 2 + 1] = ss;
            }
        }
    }
}

// ---------------------------------------------------------------------------
// Kernel 3: GroupNorm apply with INLINE combine. 2048 blocks; each block
// covers one quarter-channel (chg = blockIdx.x>>2 constant per block),
// reduces its group's 2048 pstats slots (h in batch x 64 qt x 4 wv; 16 KB,
// L2-resident, shared by 32 blocks of the same group), then applies.
// ---------------------------------------------------------------------------
__global__ __launch_bounds__(256) void gn_apply(float* __restrict__ z,
                                                const float* __restrict__ pstats,
                                                const float* __restrict__ gw,
                                                const float* __restrict__ gb)
{
    const int chg = blockIdx.x >> 2;     // global channel b*256+ch
    const int b = chg >> 8, ch = chg & 255;
    const int i = ch >> 3;               // gn group index within batch
    const int tid = threadIdx.x;

    // reduce this group's 2048 private slots
    float s = 0.f, ss = 0.f;
    for (int k = tid; k < 2048; k += 256) {       // k = hloc*256 + qt*4 + wv
        const int hloc = k >> 8, rest = k & 255;  // rest = qt*4 + wv
        const float* p = pstats +
            (((size_t)(b * 8 + hloc) * 64) * 4 + rest) * 64 + i * 2;
        s += p[0]; ss += p[1];
    }
#pragma unroll
    for (int off = 32; off > 0; off >>= 1) {
        s  += __shfl_down(s, off, 64);
        ss += __shfl_down(ss, off, 64);
    }
    __shared__ float red[8];
    __shared__ float mrs[2];
    const int w = tid >> 6;
    if ((tid & 63) == 0) { red[w * 2] = s; red[w * 2 + 1] = ss; }
    __syncthreads();
    if (tid == 0) {
        s  = red[0] + red[2] + red[4] + red[6];
        ss = red[1] + red[3] + red[5] + red[7];
        float mean = s * (1.f / 32768.f);
        float var  = ss * (1.f / 32768.f) - mean * mean;
        mrs[0] = mean;
        mrs[1] = rsqrtf(var + 1e-5f);
    }
    __syncthreads();
    const float mean = mrs[0], rstd = mrs[1];
    const float wgt = gw[ch] * rstd;
    const float bb  = gb[ch] - mean * wgt;

    const int idx = blockIdx.x * 256 + tid;       // float4 index
    float4* p4 = (float4*)z;
    float4 v = p4[idx];
    v.x = v.x * wgt + bb; v.y = v.y * wgt + bb;
    v.z = v.z * wgt + bb; v.w = v.w * wgt + bb;
    p4[idx] = v;
}

extern "C" void kernel_launch(void* const* d_in, const int* in_sizes, int n_in,
                              void* d_out, int out_size, void* d_ws, size_t ws_size,
                              hipStream_t stream)
{
    const float* points = (const float*)d_in[0];
    const float* conv_w = (const float*)d_in[1];
    const float* conv_b = (const float*)d_in[2];
    const float* gn_w   = (const float*)d_in[3];
    const float* gn_b   = (const float*)d_in[4];
    float* out = (float*)d_out;
    char* ws = (char*)d_ws;
    const size_t MB = 1024 * 1024;
    unsigned short* xqT = (unsigned short*)ws;                   // 0..4 MB
    unsigned short* xv  = (unsigned short*)(ws + 4 * MB);        // 4..8 MB
    float* pstats = (float*)(ws + 8 * MB);                       // 1 MB

    conv_kernel<<<1024, 256, 0, stream>>>(points, conv_w, conv_b, xqT, xv);
    attn_kernel<<<dim3(64, 16), 256, 0, stream>>>(xqT, xv, points, out, pstats);
    gn_apply<<<2048, 256, 0, stream>>>(out, pstats, gn_w, gn_b);
}